// Round 1
// baseline (15151.398 us; speedup 1.0000x reference)
//
#include <hip/hip_runtime.h>
#include <hip/hip_bf16.h>
#include <cstdint>

// Problem dims
#define T_STEPS 128
#define BATCH   32
#define VOCAB   50000
#define EDIM    512
#define HDIM    512
#define GDIM    2048          // 4*H
#define MROWS   4096          // T*B
#define VPAD    50048         // 391 * 128 (padded N for decode GEMM)

typedef short bf16x8 __attribute__((ext_vector_type(8)));
typedef float f32x4  __attribute__((ext_vector_type(4)));
typedef unsigned short us4 __attribute__((ext_vector_type(4)));
typedef unsigned short us8 __attribute__((ext_vector_type(8)));

__device__ __forceinline__ float sigmoidf_(float x) { return 1.0f / (1.0f + expf(-x)); }

// round-to-nearest-even fp32 -> bf16 bits
__device__ __forceinline__ unsigned short f2bf(float f) {
    unsigned int u = __float_as_uint(f);
    u = (u + 0x7fffu + ((u >> 16) & 1u)) >> 16;
    return (unsigned short)u;
}

// ---------------------------------------------------------------------------
// Prologue kernels
// ---------------------------------------------------------------------------

// fp32 -> bf16 bits, n multiple of 8
__global__ __launch_bounds__(256) void conv_bf16(const float* __restrict__ src,
                                                 unsigned short* __restrict__ dst, long n) {
    long i = ((long)blockIdx.x * 256 + threadIdx.x) * 8;
    if (i >= n) return;
    float4 a = *(const float4*)(src + i);
    float4 b = *(const float4*)(src + i + 4);
    us8 v;
    v[0] = f2bf(a.x); v[1] = f2bf(a.y); v[2] = f2bf(a.z); v[3] = f2bf(a.w);
    v[4] = f2bf(b.x); v[5] = f2bf(b.y); v[6] = f2bf(b.z); v[7] = f2bf(b.w);
    *(us8*)(dst + i) = v;
}

// dec_W [50000x512] fp32 -> [50048x512] bf16 with zero pad rows
__global__ __launch_bounds__(256) void conv_decw(const float* __restrict__ src,
                                                 unsigned short* __restrict__ dst) {
    long i = ((long)blockIdx.x * 256 + threadIdx.x) * 8;
    if (i >= (long)VPAD * EDIM) return;
    long row = i >> 9;
    us8 v;
    if (row < VOCAB) {
        float4 a = *(const float4*)(src + i);
        float4 b = *(const float4*)(src + i + 4);
        v[0] = f2bf(a.x); v[1] = f2bf(a.y); v[2] = f2bf(a.z); v[3] = f2bf(a.w);
        v[4] = f2bf(b.x); v[5] = f2bf(b.y); v[6] = f2bf(b.z); v[7] = f2bf(b.w);
    } else {
        v = (us8)0;
    }
    *(us8*)(dst + i) = v;
}

// X[r, :] = bf16(emb[seq[r], :]) for r in [0, T*B)
__global__ __launch_bounds__(256) void gather_x(const int* __restrict__ seq,
                                                const float* __restrict__ emb,
                                                unsigned short* __restrict__ Xbf) {
    long i = ((long)blockIdx.x * 256 + threadIdx.x) * 4;
    if (i >= (long)MROWS * EDIM) return;
    int r   = (int)(i >> 9);
    int col = (int)(i & 511);
    const float* er = emb + (long)seq[r] * EDIM + col;
    float4 e = *(const float4*)er;
    us4 v;
    v[0] = f2bf(e.x); v[1] = f2bf(e.y); v[2] = f2bf(e.z); v[3] = f2bf(e.w);
    *(us4*)(Xbf + i) = v;
}

// c0[b,h] = emb[word[b]] . w2h_W[h] + w2h_b[h]; both layers start with c0, h=0
__global__ __launch_bounds__(256) void init_c0(const int* __restrict__ word,
                                               const float* __restrict__ emb,
                                               const float* __restrict__ w2hW,
                                               const float* __restrict__ w2hb,
                                               float* __restrict__ c0s, float* __restrict__ c1s,
                                               float* __restrict__ h0A, float* __restrict__ h1A) {
    const int idx = blockIdx.x * 256 + threadIdx.x;   // 0..16383
    const int b = idx >> 9, hh = idx & 511;
    const float* er = emb + (long)word[b] * EDIM;
    const float* wr = w2hW + (long)hh * EDIM;
    float acc = w2hb[hh];
    #pragma unroll 4
    for (int k = 0; k < EDIM; k += 4) {
        float4 e4 = *(const float4*)(er + k);
        float4 w4 = *(const float4*)(wr + k);
        acc += e4.x * w4.x + e4.y * w4.y + e4.z * w4.z + e4.w * w4.w;
    }
    c0s[idx] = acc;
    c1s[idx] = acc;
    h0A[idx] = 0.0f;
    h1A[idx] = 0.0f;
}

// ---------------------------------------------------------------------------
// MFMA GEMM: C[m,n] = sum_k A[m,k]*Bt[n,k] (+bias1[n] +bias2[n])
// A [Mx K] bf16 row-major, Bt [Npad x K] bf16 row-major. 128x128 tile, BK=64,
// 4 waves (2x2), each wave 64x64 via 4x4 fragments of 16x16x32 bf16 MFMA.
// M multiple of 128; Npad multiple of 128; store guarded by col < Nreal.
// ---------------------------------------------------------------------------
__global__ __launch_bounds__(256) void gemm_bt128(const unsigned short* __restrict__ A,
                                                  const unsigned short* __restrict__ Bt,
                                                  float* __restrict__ C,
                                                  const float* __restrict__ bias1,
                                                  const float* __restrict__ bias2,
                                                  int K, int Nreal, long ldc, int ntn) {
    __shared__ __align__(16) unsigned short As[128 * 64];
    __shared__ __align__(16) unsigned short Bs[128 * 64];
    const int tid  = threadIdx.x;
    const long m0  = (long)(blockIdx.x / ntn) * 128;
    const long n0  = (long)(blockIdx.x % ntn) * 128;
    const int lane = tid & 63;
    const int wave = tid >> 6;
    const int wr = wave >> 1, wc = wave & 1;
    const int fr = lane & 15, fq = lane >> 4;

    f32x4 acc[4][4];
    #pragma unroll
    for (int i = 0; i < 4; ++i)
        #pragma unroll
        for (int j = 0; j < 4; ++j) acc[i][j] = (f32x4)0.0f;

    const int srow = tid >> 3;         // 0..31: row within 32-row staging chunk
    const int scol = (tid & 7) * 8;    // 0..56: bf16 col offset (16B per lane)

    for (int kt = 0; kt < K; kt += 64) {
        #pragma unroll
        for (int i = 0; i < 4; ++i) {
            const unsigned short* ga = A  + (m0 + i * 32 + srow) * K + kt + scol;
            const unsigned short* gb = Bt + (n0 + i * 32 + srow) * K + kt + scol;
            __builtin_amdgcn_global_load_lds((const __attribute__((address_space(1))) void*)ga,
                                             (__attribute__((address_space(3))) void*)(As + i * 2048 + tid * 8),
                                             16, 0, 0);
            __builtin_amdgcn_global_load_lds((const __attribute__((address_space(1))) void*)gb,
                                             (__attribute__((address_space(3))) void*)(Bs + i * 2048 + tid * 8),
                                             16, 0, 0);
        }
        asm volatile("s_waitcnt vmcnt(0)" ::: "memory");
        __syncthreads();
        #pragma unroll
        for (int ks = 0; ks < 64; ks += 32) {
            bf16x8 af[4], bfr[4];
            #pragma unroll
            for (int mi = 0; mi < 4; ++mi)
                af[mi] = *(const bf16x8*)&As[(wr * 64 + mi * 16 + fr) * 64 + ks + fq * 8];
            #pragma unroll
            for (int ni = 0; ni < 4; ++ni)
                bfr[ni] = *(const bf16x8*)&Bs[(wc * 64 + ni * 16 + fr) * 64 + ks + fq * 8];
            #pragma unroll
            for (int mi = 0; mi < 4; ++mi)
                #pragma unroll
                for (int ni = 0; ni < 4; ++ni)
                    acc[mi][ni] = __builtin_amdgcn_mfma_f32_16x16x32_bf16(af[mi], bfr[ni], acc[mi][ni], 0, 0, 0);
        }
        __syncthreads();
    }

    #pragma unroll
    for (int mi = 0; mi < 4; ++mi) {
        const long row = m0 + wr * 64 + mi * 16 + fq * 4;
        #pragma unroll
        for (int ni = 0; ni < 4; ++ni) {
            const long col = n0 + wc * 64 + ni * 16 + fr;
            if (col < Nreal) {
                float bs = (bias1 ? bias1[col] : 0.0f) + (bias2 ? bias2[col] : 0.0f);
                #pragma unroll
                for (int r = 0; r < 4; ++r)
                    C[(row + r) * ldc + col] = acc[mi][ni][r] + bs;
            }
        }
    }
}

// ---------------------------------------------------------------------------
// LSTM step (skewed): blocks 0..63 do layer0 step t, blocks 64..127 do layer1
// step t-1. Per layer-block: 8 batch rows x 32 hidden cols; thread = (bl, nl).
// h-state ping-pong (A/B by step parity) avoids cross-block h races; c-state
// is element-owned (same thread reads+writes), safe single-buffered.
// ---------------------------------------------------------------------------
__device__ __forceinline__ void dot4(const float* __restrict__ w0,
                                     const float* __restrict__ sv,
                                     float& ai, float& af, float& ag, float& ao) {
    const float* wi = w0;
    const float* wf = w0 + 512 * 512;
    const float* wg = w0 + 2 * 512 * 512;
    const float* wo = w0 + 3 * 512 * 512;
    #pragma unroll 4
    for (int k = 0; k < 512; k += 4) {
        const float4 s4 = *(const float4*)(sv + k);
        const float4 a4 = *(const float4*)(wi + k);
        const float4 b4 = *(const float4*)(wf + k);
        const float4 c4 = *(const float4*)(wg + k);
        const float4 d4 = *(const float4*)(wo + k);
        ai += s4.x * a4.x + s4.y * a4.y + s4.z * a4.z + s4.w * a4.w;
        af += s4.x * b4.x + s4.y * b4.y + s4.z * b4.z + s4.w * b4.w;
        ag += s4.x * c4.x + s4.y * c4.y + s4.z * c4.z + s4.w * c4.w;
        ao += s4.x * d4.x + s4.y * d4.y + s4.z * d4.z + s4.w * d4.w;
    }
}

__global__ __launch_bounds__(256) void lstm_step(const float* __restrict__ G0,
                                                 const float* __restrict__ Whh0,
                                                 const float* __restrict__ Wih1,
                                                 const float* __restrict__ Whh1,
                                                 const float* __restrict__ bih1,
                                                 const float* __restrict__ bhh1,
                                                 float* __restrict__ y0,
                                                 unsigned short* __restrict__ y1bf,
                                                 float* __restrict__ h0A, float* __restrict__ h0B,
                                                 float* __restrict__ c0s,
                                                 float* __restrict__ h1A, float* __restrict__ h1B,
                                                 float* __restrict__ c1s,
                                                 int t) {
    __shared__ float sx[8 * 512];
    __shared__ float sh[8 * 512];
    const int tid = threadIdx.x;
    int bid = blockIdx.x;

    if (bid < 64) {
        // ---- layer 0, step t ----
        if (t >= T_STEPS) return;
        const int b0 = (bid >> 4) * 8;
        const int n0 = (bid & 15) * 32;
        const float* hin = (t & 1) ? h0B : h0A;
        float* hout      = (t & 1) ? h0A : h0B;
        for (int i = tid; i < 8 * 512; i += 256) sh[i] = hin[b0 * 512 + i];
        __syncthreads();
        const int bl = tid >> 5, nl = tid & 31;
        const int b = b0 + bl, n = n0 + nl;
        const float* g0p = G0 + (long)(t * BATCH + b) * GDIM;
        float ai = g0p[n], af = g0p[512 + n], ag = g0p[1024 + n], ao = g0p[1536 + n];
        dot4(Whh0 + (long)n * 512, sh + bl * 512, ai, af, ag, ao);
        const int si = b * HDIM + n;
        float c = sigmoidf_(af) * c0s[si] + sigmoidf_(ai) * tanhf(ag);
        float h = sigmoidf_(ao) * tanhf(c);
        c0s[si]  = c;
        hout[si] = h;
        y0[(long)(t * BATCH + b) * HDIM + n] = h;
    } else {
        // ---- layer 1, step t-1 ----
        const int tt = t - 1;
        if (tt < 0) return;
        bid -= 64;
        const int b0 = (bid >> 4) * 8;
        const int n0 = (bid & 15) * 32;
        const float* hin = (tt & 1) ? h1B : h1A;
        float* hout      = (tt & 1) ? h1A : h1B;
        const float* xrow = y0 + (long)(tt * BATCH + b0) * HDIM;
        for (int i = tid; i < 8 * 512; i += 256) {
            sx[i] = xrow[i];
            sh[i] = hin[b0 * 512 + i];
        }
        __syncthreads();
        const int bl = tid >> 5, nl = tid & 31;
        const int b = b0 + bl, n = n0 + nl;
        float ai = bih1[n]        + bhh1[n];
        float af = bih1[512 + n]  + bhh1[512 + n];
        float ag = bih1[1024 + n] + bhh1[1024 + n];
        float ao = bih1[1536 + n] + bhh1[1536 + n];
        dot4(Wih1 + (long)n * 512, sx + bl * 512, ai, af, ag, ao);
        dot4(Whh1 + (long)n * 512, sh + bl * 512, ai, af, ag, ao);
        const int si = b * HDIM + n;
        float c = sigmoidf_(af) * c1s[si] + sigmoidf_(ai) * tanhf(ag);
        float h = sigmoidf_(ao) * tanhf(c);
        c1s[si]  = c;
        hout[si] = h;
        y1bf[(long)(tt * BATCH + b) * HDIM + n] = f2bf(h);
    }
}

// h_final/c_final -> d_out tail: [h_f0 | h_f1 | c_f0 | c_f1], 16384 floats each
__global__ __launch_bounds__(256) void finalize_states(const float* __restrict__ h0A,
                                                       const float* __restrict__ h1A,
                                                       const float* __restrict__ c0s,
                                                       const float* __restrict__ c1s,
                                                       float* __restrict__ out) {
    const int idx = blockIdx.x * 256 + threadIdx.x;   // 0..65535
    const long base = (long)MROWS * VOCAB;
    float v;
    if (idx < 16384)      v = h0A[idx];
    else if (idx < 32768) v = h1A[idx - 16384];
    else if (idx < 49152) v = c0s[idx - 32768];
    else                  v = c1s[idx - 49152];
    out[base + idx] = v;
}

// ---------------------------------------------------------------------------
extern "C" void kernel_launch(void* const* d_in, const int* in_sizes, int n_in,
                              void* d_out, int out_size, void* d_ws, size_t ws_size,
                              hipStream_t stream) {
    const int*   word  = (const int*)d_in[0];
    const int*   seq   = (const int*)d_in[1];
    const float* emb   = (const float*)d_in[2];
    const float* w2hW  = (const float*)d_in[3];
    const float* w2hb  = (const float*)d_in[4];
    const float* Wih0  = (const float*)d_in[5];
    const float* Whh0  = (const float*)d_in[6];
    const float* bih0  = (const float*)d_in[7];
    const float* bhh0  = (const float*)d_in[8];
    const float* Wih1  = (const float*)d_in[9];
    const float* Whh1  = (const float*)d_in[10];
    const float* bih1  = (const float*)d_in[11];
    const float* bhh1  = (const float*)d_in[12];
    const float* dec_W = (const float*)d_in[13];
    const float* dec_b = (const float*)d_in[14];
    float* out = (float*)d_out;

    char* ws = (char*)d_ws;
    size_t off = 0;
    float*          G0    = (float*)(ws + off);          off += (size_t)MROWS * GDIM * 4;   // 33.5 MB
    unsigned short* Xbf   = (unsigned short*)(ws + off); off += (size_t)MROWS * EDIM * 2;   //  4.2 MB
    unsigned short* Wih0b = (unsigned short*)(ws + off); off += (size_t)GDIM  * EDIM * 2;   //  2.1 MB
    unsigned short* decWb = (unsigned short*)(ws + off); off += (size_t)VPAD  * EDIM * 2;   // 51.2 MB
    float*          y0    = (float*)(ws + off);          off += (size_t)MROWS * HDIM * 4;   //  8.4 MB
    unsigned short* y1bf  = (unsigned short*)(ws + off); off += (size_t)MROWS * HDIM * 2;   //  4.2 MB
    float* h0A = (float*)(ws + off); off += (size_t)BATCH * HDIM * 4;
    float* h0B = (float*)(ws + off); off += (size_t)BATCH * HDIM * 4;
    float* c0s = (float*)(ws + off); off += (size_t)BATCH * HDIM * 4;
    float* h1A = (float*)(ws + off); off += (size_t)BATCH * HDIM * 4;
    float* h1B = (float*)(ws + off); off += (size_t)BATCH * HDIM * 4;
    float* c1s = (float*)(ws + off); off += (size_t)BATCH * HDIM * 4;
    // total ~104 MB of d_ws

    // prologue (all parallel, no deps between them except gemm needs converts)
    conv_decw<<<12512, 256, 0, stream>>>(dec_W, decWb);
    conv_bf16<<<512, 256, 0, stream>>>(Wih0, Wih0b, (long)GDIM * EDIM);
    gather_x<<<2048, 256, 0, stream>>>(seq, emb, Xbf);
    init_c0<<<64, 256, 0, stream>>>(word, emb, w2hW, w2hb, c0s, c1s, h0A, h1A);

    // G0 = X @ Wih0^T + bih0 + bhh0   [4096 x 2048], K=512
    gemm_bt128<<<32 * 16, 256, 0, stream>>>(Xbf, Wih0b, G0, bih0, bhh0,
                                            512, GDIM, (long)GDIM, 16);

    // skewed recurrence: layer0 step t || layer1 step t-1
    for (int t = 0; t <= T_STEPS; ++t)
        lstm_step<<<128, 256, 0, stream>>>(G0, Whh0, Wih1, Whh1, bih1, bhh1,
                                           y0, y1bf, h0A, h0B, c0s, h1A, h1B, c1s, t);

    // decoded = y1 @ dec_W^T + dec_b   [4096 x 50000], K=512
    gemm_bt128<<<32 * 391, 256, 0, stream>>>(y1bf, decWb, out, dec_b, nullptr,
                                             512, VOCAB, (long)VOCAB, 391);

    finalize_states<<<256, 256, 0, stream>>>(h0A, h1A, c0s, c1s, out);
}

// Round 2
// 2966.618 us; speedup vs baseline: 5.1073x; 5.1073x over previous
//
#include <hip/hip_runtime.h>
#include <hip/hip_bf16.h>
#include <cstdint>

// Problem dims
#define T_STEPS 128
#define BATCH   32
#define VOCAB   50000
#define EDIM    512
#define HDIM    512
#define GDIM    2048          // 4*H
#define MROWS   4096          // T*B
#define VPAD    50048         // 391 * 128 (padded N for decode GEMM)

typedef short bf16x8 __attribute__((ext_vector_type(8)));
typedef float f32x4  __attribute__((ext_vector_type(4)));
typedef unsigned short us4 __attribute__((ext_vector_type(4)));
typedef unsigned short us8 __attribute__((ext_vector_type(8)));

__device__ __forceinline__ float sigmoidf_(float x) { return 1.0f / (1.0f + expf(-x)); }

// round-to-nearest-even fp32 -> bf16 bits
__device__ __forceinline__ unsigned short f2bf(float f) {
    unsigned int u = __float_as_uint(f);
    u = (u + 0x7fffu + ((u >> 16) & 1u)) >> 16;
    return (unsigned short)u;
}

// ---------------------------------------------------------------------------
// Prologue kernels
// ---------------------------------------------------------------------------

// dec_W [50000x512] fp32 -> [50048x512] bf16 with zero pad rows
__global__ __launch_bounds__(256) void conv_decw(const float* __restrict__ src,
                                                 unsigned short* __restrict__ dst) {
    long i = ((long)blockIdx.x * 256 + threadIdx.x) * 8;
    if (i >= (long)VPAD * EDIM) return;
    long row = i >> 9;
    us8 v;
    if (row < VOCAB) {
        float4 a = *(const float4*)(src + i);
        float4 b = *(const float4*)(src + i + 4);
        v[0] = f2bf(a.x); v[1] = f2bf(a.y); v[2] = f2bf(a.z); v[3] = f2bf(a.w);
        v[4] = f2bf(b.x); v[5] = f2bf(b.y); v[6] = f2bf(b.z); v[7] = f2bf(b.w);
    } else {
        v = (us8)0;
    }
    *(us8*)(dst + i) = v;
}

// Gate-interleaved pack+convert: dst[n'][k] = bf16(src[(n'&3)*512 + (n'>>2)][k])
// (packed order: unit u, gate g -> n' = u*4+g; orig rows are [i|f|g|o] blocks)
__global__ __launch_bounds__(64) void pack_conv(const float* __restrict__ src,
                                                unsigned short* __restrict__ dst) {
    const int n = blockIdx.x;                       // packed row 0..2047
    const int orig = (n & 3) * 512 + (n >> 2);
    const int k = threadIdx.x * 8;
    const float* s = src + (long)orig * 512 + k;
    float4 a = *(const float4*)s;
    float4 b = *(const float4*)(s + 4);
    us8 v;
    v[0] = f2bf(a.x); v[1] = f2bf(a.y); v[2] = f2bf(a.z); v[3] = f2bf(a.w);
    v[4] = f2bf(b.x); v[5] = f2bf(b.y); v[6] = f2bf(b.z); v[7] = f2bf(b.w);
    *(us8*)(dst + (long)n * 512 + k) = v;
}

// packed bias sums
__global__ __launch_bounds__(256) void pack_bias(const float* __restrict__ bih0,
                                                 const float* __restrict__ bhh0,
                                                 const float* __restrict__ bih1,
                                                 const float* __restrict__ bhh1,
                                                 float* __restrict__ b0p,
                                                 float* __restrict__ b1p) {
    const int n = blockIdx.x * 256 + threadIdx.x;   // 0..2047
    const int orig = (n & 3) * 512 + (n >> 2);
    b0p[n] = bih0[orig] + bhh0[orig];
    b1p[n] = bih1[orig] + bhh1[orig];
}

// X[r, :] = bf16(emb[seq[r], :]) for r in [0, T*B)
__global__ __launch_bounds__(256) void gather_x(const int* __restrict__ seq,
                                                const float* __restrict__ emb,
                                                unsigned short* __restrict__ Xbf) {
    long i = ((long)blockIdx.x * 256 + threadIdx.x) * 4;
    if (i >= (long)MROWS * EDIM) return;
    int r   = (int)(i >> 9);
    int col = (int)(i & 511);
    const float* er = emb + (long)seq[r] * EDIM + col;
    float4 e = *(const float4*)er;
    us4 v;
    v[0] = f2bf(e.x); v[1] = f2bf(e.y); v[2] = f2bf(e.z); v[3] = f2bf(e.w);
    *(us4*)(Xbf + i) = v;
}

// c0[b,h] = emb[word[b]] . w2h_W[h] + w2h_b[h]; both layers start with c0, h=0 (bf16)
__global__ __launch_bounds__(256) void init_c0(const int* __restrict__ word,
                                               const float* __restrict__ emb,
                                               const float* __restrict__ w2hW,
                                               const float* __restrict__ w2hb,
                                               float* __restrict__ c0s, float* __restrict__ c1s,
                                               unsigned short* __restrict__ h0A,
                                               unsigned short* __restrict__ h1A) {
    const int idx = blockIdx.x * 256 + threadIdx.x;   // 0..16383
    const int b = idx >> 9, hh = idx & 511;
    const float* er = emb + (long)word[b] * EDIM;
    const float* wr = w2hW + (long)hh * EDIM;
    float acc = w2hb[hh];
    #pragma unroll 4
    for (int k = 0; k < EDIM; k += 4) {
        float4 e4 = *(const float4*)(er + k);
        float4 w4 = *(const float4*)(wr + k);
        acc += e4.x * w4.x + e4.y * w4.y + e4.z * w4.z + e4.w * w4.w;
    }
    c0s[idx] = acc;
    c1s[idx] = acc;
    h0A[idx] = 0;
    h1A[idx] = 0;
}

// ---------------------------------------------------------------------------
// MFMA GEMM: C[m,n] = sum_k A[m,k]*Bt[n,k] (+bias1[n] +bias2[n])
// ---------------------------------------------------------------------------
__global__ __launch_bounds__(256) void gemm_bt128(const unsigned short* __restrict__ A,
                                                  const unsigned short* __restrict__ Bt,
                                                  float* __restrict__ C,
                                                  const float* __restrict__ bias1,
                                                  const float* __restrict__ bias2,
                                                  int K, int Nreal, long ldc, int ntn) {
    __shared__ __align__(16) unsigned short As[128 * 64];
    __shared__ __align__(16) unsigned short Bs[128 * 64];
    const int tid  = threadIdx.x;
    const long m0  = (long)(blockIdx.x / ntn) * 128;
    const long n0  = (long)(blockIdx.x % ntn) * 128;
    const int lane = tid & 63;
    const int wave = tid >> 6;
    const int wr = wave >> 1, wc = wave & 1;
    const int fr = lane & 15, fq = lane >> 4;

    f32x4 acc[4][4];
    #pragma unroll
    for (int i = 0; i < 4; ++i)
        #pragma unroll
        for (int j = 0; j < 4; ++j) acc[i][j] = (f32x4)0.0f;

    const int srow = tid >> 3;
    const int scol = (tid & 7) * 8;

    for (int kt = 0; kt < K; kt += 64) {
        #pragma unroll
        for (int i = 0; i < 4; ++i) {
            const unsigned short* ga = A  + (m0 + i * 32 + srow) * K + kt + scol;
            const unsigned short* gb = Bt + (n0 + i * 32 + srow) * K + kt + scol;
            __builtin_amdgcn_global_load_lds((const __attribute__((address_space(1))) void*)ga,
                                             (__attribute__((address_space(3))) void*)(As + i * 2048 + tid * 8),
                                             16, 0, 0);
            __builtin_amdgcn_global_load_lds((const __attribute__((address_space(1))) void*)gb,
                                             (__attribute__((address_space(3))) void*)(Bs + i * 2048 + tid * 8),
                                             16, 0, 0);
        }
        asm volatile("s_waitcnt vmcnt(0)" ::: "memory");
        __syncthreads();
        #pragma unroll
        for (int ks = 0; ks < 64; ks += 32) {
            bf16x8 af[4], bfr[4];
            #pragma unroll
            for (int mi = 0; mi < 4; ++mi)
                af[mi] = *(const bf16x8*)&As[(wr * 64 + mi * 16 + fr) * 64 + ks + fq * 8];
            #pragma unroll
            for (int ni = 0; ni < 4; ++ni)
                bfr[ni] = *(const bf16x8*)&Bs[(wc * 64 + ni * 16 + fr) * 64 + ks + fq * 8];
            #pragma unroll
            for (int mi = 0; mi < 4; ++mi)
                #pragma unroll
                for (int ni = 0; ni < 4; ++ni)
                    acc[mi][ni] = __builtin_amdgcn_mfma_f32_16x16x32_bf16(af[mi], bfr[ni], acc[mi][ni], 0, 0, 0);
        }
        __syncthreads();
    }

    #pragma unroll
    for (int mi = 0; mi < 4; ++mi) {
        const long row = m0 + wr * 64 + mi * 16 + fq * 4;
        #pragma unroll
        for (int ni = 0; ni < 4; ++ni) {
            const long col = n0 + wc * 64 + ni * 16 + fr;
            if (col < Nreal) {
                float bs = (bias1 ? bias1[col] : 0.0f) + (bias2 ? bias2[col] : 0.0f);
                #pragma unroll
                for (int r = 0; r < 4; ++r)
                    C[(row + r) * ldc + col] = acc[mi][ni][r] + bs;
            }
        }
    }
}

// ---------------------------------------------------------------------------
// MFMA LSTM step (skewed): blocks 0..15 layer0 step t, 16..31 layer1 step t-1.
// Each block: 32(batch) x 128(packed gate cols); 4 waves, each 32x32 via
// 2x2 fragments of mfma_f32_16x16x32_bf16. Packed order n' = unit*4 + gate
// keeps i/f/g/o adjacent so pointwise is block-local via a small LDS tile.
// h-state bf16 ping-pong; c-state fp32 element-owned.
// ---------------------------------------------------------------------------
__global__ __launch_bounds__(256) void lstm_step_mfma(
        const float* __restrict__ G0,              // [4096][2048] packed, biases folded
        const unsigned short* __restrict__ Whh0p,  // [2048][512] packed bf16
        const unsigned short* __restrict__ Wih1p,
        const unsigned short* __restrict__ Whh1p,
        const float* __restrict__ b1p,             // [2048] packed bias sum layer1
        unsigned short* __restrict__ y0bf,         // [T][32][512] bf16
        unsigned short* __restrict__ y1bf,         // [T][32][512] bf16
        unsigned short* __restrict__ h0A, unsigned short* __restrict__ h0B,
        float* __restrict__ c0s,
        unsigned short* __restrict__ h1A, unsigned short* __restrict__ h1B,
        float* __restrict__ c1s,
        float* __restrict__ hf,                    // [2][32][512] fp32 final h
        int t) {
    __shared__ float gl[4][32][32];
    int bid = blockIdx.x;
    const int tid  = threadIdx.x;
    const int wv   = tid >> 6, lane = tid & 63;
    const int fr   = lane & 15, fq = lane >> 4;

    int layer, tt;
    if (bid < 16) { layer = 0; tt = t;     if (tt >= T_STEPS) return; }
    else          { layer = 1; tt = t - 1; if (tt < 0) return; bid -= 16; }

    const unsigned short* hin;
    unsigned short* hout;
    float* cs;
    if (layer == 0) { hin = (tt & 1) ? h0B : h0A; hout = (tt & 1) ? h0A : h0B; cs = c0s; }
    else            { hin = (tt & 1) ? h1B : h1A; hout = (tt & 1) ? h1A : h1B; cs = c1s; }

    const int n_base = bid * 128 + wv * 32;   // packed col base for this wave
    const int koff   = fq * 8;

    f32x4 acc[2][2];
    acc[0][0] = (f32x4)0.0f; acc[0][1] = (f32x4)0.0f;
    acc[1][0] = (f32x4)0.0f; acc[1][1] = (f32x4)0.0f;

    {   // gates += h_in @ Whh^T
        const unsigned short* W  = (layer == 0) ? Whh0p : Whh1p;
        const unsigned short* A0 = hin + fr * 512 + koff;
        const unsigned short* A1 = hin + (16 + fr) * 512 + koff;
        const unsigned short* B0 = W + (n_base + fr) * 512 + koff;
        const unsigned short* B1 = W + (n_base + 16 + fr) * 512 + koff;
        #pragma unroll 4
        for (int kt = 0; kt < 512; kt += 32) {
            bf16x8 a0 = *(const bf16x8*)(A0 + kt);
            bf16x8 a1 = *(const bf16x8*)(A1 + kt);
            bf16x8 b0 = *(const bf16x8*)(B0 + kt);
            bf16x8 b1 = *(const bf16x8*)(B1 + kt);
            acc[0][0] = __builtin_amdgcn_mfma_f32_16x16x32_bf16(a0, b0, acc[0][0], 0, 0, 0);
            acc[0][1] = __builtin_amdgcn_mfma_f32_16x16x32_bf16(a0, b1, acc[0][1], 0, 0, 0);
            acc[1][0] = __builtin_amdgcn_mfma_f32_16x16x32_bf16(a1, b0, acc[1][0], 0, 0, 0);
            acc[1][1] = __builtin_amdgcn_mfma_f32_16x16x32_bf16(a1, b1, acc[1][1], 0, 0, 0);
        }
    }
    if (layer == 1) {   // gates += y0[tt] @ Wih1^T
        const unsigned short* X  = y0bf + (long)tt * (BATCH * HDIM);
        const unsigned short* A0 = X + fr * 512 + koff;
        const unsigned short* A1 = X + (16 + fr) * 512 + koff;
        const unsigned short* B0 = Wih1p + (n_base + fr) * 512 + koff;
        const unsigned short* B1 = Wih1p + (n_base + 16 + fr) * 512 + koff;
        #pragma unroll 4
        for (int kt = 0; kt < 512; kt += 32) {
            bf16x8 a0 = *(const bf16x8*)(A0 + kt);
            bf16x8 a1 = *(const bf16x8*)(A1 + kt);
            bf16x8 b0 = *(const bf16x8*)(B0 + kt);
            bf16x8 b1 = *(const bf16x8*)(B1 + kt);
            acc[0][0] = __builtin_amdgcn_mfma_f32_16x16x32_bf16(a0, b0, acc[0][0], 0, 0, 0);
            acc[0][1] = __builtin_amdgcn_mfma_f32_16x16x32_bf16(a0, b1, acc[0][1], 0, 0, 0);
            acc[1][0] = __builtin_amdgcn_mfma_f32_16x16x32_bf16(a1, b0, acc[1][0], 0, 0, 0);
            acc[1][1] = __builtin_amdgcn_mfma_f32_16x16x32_bf16(a1, b1, acc[1][1], 0, 0, 0);
        }
    }

    // acc fragments -> per-wave LDS tile [batch 32][packed col 32]
    #pragma unroll
    for (int mi = 0; mi < 2; ++mi)
        #pragma unroll
        for (int ni = 0; ni < 2; ++ni)
            #pragma unroll
            for (int r = 0; r < 4; ++r)
                gl[wv][mi * 16 + fq * 4 + r][ni * 16 + fr] = acc[mi][ni][r];
    __syncthreads();

    // pointwise: each lane handles 4 (batch, unit) pairs of its wave's tile
    const int u     = lane & 7;          // unit within wave tile (8 units)
    const int b0r   = lane >> 3;         // 0..7
    const int ubase = n_base >> 2;       // global unit base = bid*32 + wv*8
    #pragma unroll
    for (int r = 0; r < 4; ++r) {
        const int b = b0r + r * 8;
        float4 g4 = *(const float4*)&gl[wv][b][u * 4];
        float4 ad;
        if (layer == 0) ad = *(const float4*)(G0 + ((long)tt * BATCH + b) * GDIM + n_base + u * 4);
        else            ad = *(const float4*)(b1p + n_base + u * 4);
        const float vi = g4.x + ad.x, vf = g4.y + ad.y;
        const float vg = g4.z + ad.z, vo = g4.w + ad.w;
        const int si = b * HDIM + ubase + u;
        float c = sigmoidf_(vf) * cs[si] + sigmoidf_(vi) * tanhf(vg);
        float h = sigmoidf_(vo) * tanhf(c);
        cs[si] = c;
        const unsigned short hb = f2bf(h);
        hout[si] = hb;
        if (layer == 0) y0bf[(long)tt * (BATCH * HDIM) + si] = hb;
        else            y1bf[(long)tt * (BATCH * HDIM) + si] = hb;
        if (tt == T_STEPS - 1) hf[layer * (BATCH * HDIM) + si] = h;
    }
}

// d_out tail: [h_f0 | h_f1 | c_f0 | c_f1], 16384 floats each
__global__ __launch_bounds__(256) void finalize_states(const float* __restrict__ hf,
                                                       const float* __restrict__ c0s,
                                                       const float* __restrict__ c1s,
                                                       float* __restrict__ out) {
    const int idx = blockIdx.x * 256 + threadIdx.x;   // 0..65535
    const long base = (long)MROWS * VOCAB;
    float v;
    if (idx < 32768)      v = hf[idx];
    else if (idx < 49152) v = c0s[idx - 32768];
    else                  v = c1s[idx - 49152];
    out[base + idx] = v;
}

// ---------------------------------------------------------------------------
extern "C" void kernel_launch(void* const* d_in, const int* in_sizes, int n_in,
                              void* d_out, int out_size, void* d_ws, size_t ws_size,
                              hipStream_t stream) {
    const int*   word  = (const int*)d_in[0];
    const int*   seq   = (const int*)d_in[1];
    const float* emb   = (const float*)d_in[2];
    const float* w2hW  = (const float*)d_in[3];
    const float* w2hb  = (const float*)d_in[4];
    const float* Wih0  = (const float*)d_in[5];
    const float* Whh0  = (const float*)d_in[6];
    const float* bih0  = (const float*)d_in[7];
    const float* bhh0  = (const float*)d_in[8];
    const float* Wih1  = (const float*)d_in[9];
    const float* Whh1  = (const float*)d_in[10];
    const float* bih1  = (const float*)d_in[11];
    const float* bhh1  = (const float*)d_in[12];
    const float* dec_W = (const float*)d_in[13];
    const float* dec_b = (const float*)d_in[14];
    float* out = (float*)d_out;

    char* ws = (char*)d_ws;
    size_t off = 0;
    float*          G0    = (float*)(ws + off);          off += (size_t)MROWS * GDIM * 4;   // 33.5 MB
    unsigned short* Xbf   = (unsigned short*)(ws + off); off += (size_t)MROWS * EDIM * 2;   //  4.2 MB
    unsigned short* Wih0p = (unsigned short*)(ws + off); off += (size_t)GDIM  * EDIM * 2;   //  2.1 MB
    unsigned short* Whh0p = (unsigned short*)(ws + off); off += (size_t)GDIM  * HDIM * 2;   //  2.1 MB
    unsigned short* Wih1p = (unsigned short*)(ws + off); off += (size_t)GDIM  * HDIM * 2;   //  2.1 MB
    unsigned short* Whh1p = (unsigned short*)(ws + off); off += (size_t)GDIM  * HDIM * 2;   //  2.1 MB
    unsigned short* decWb = (unsigned short*)(ws + off); off += (size_t)VPAD  * EDIM * 2;   // 51.2 MB
    unsigned short* y0bf  = (unsigned short*)(ws + off); off += (size_t)MROWS * HDIM * 2;   //  4.2 MB
    unsigned short* y1bf  = (unsigned short*)(ws + off); off += (size_t)MROWS * HDIM * 2;   //  4.2 MB
    float* b0p = (float*)(ws + off); off += (size_t)GDIM * 4;
    float* b1p = (float*)(ws + off); off += (size_t)GDIM * 4;
    unsigned short* h0A = (unsigned short*)(ws + off); off += (size_t)BATCH * HDIM * 2;
    unsigned short* h0B = (unsigned short*)(ws + off); off += (size_t)BATCH * HDIM * 2;
    unsigned short* h1A = (unsigned short*)(ws + off); off += (size_t)BATCH * HDIM * 2;
    unsigned short* h1B = (unsigned short*)(ws + off); off += (size_t)BATCH * HDIM * 2;
    float* c0s = (float*)(ws + off); off += (size_t)BATCH * HDIM * 4;
    float* c1s = (float*)(ws + off); off += (size_t)BATCH * HDIM * 4;
    float* hf  = (float*)(ws + off); off += (size_t)2 * BATCH * HDIM * 4;
    // total ~106 MB of d_ws

    // prologue (parallel)
    conv_decw<<<12512, 256, 0, stream>>>(dec_W, decWb);
    pack_conv<<<2048, 64, 0, stream>>>(Wih0, Wih0p);
    pack_conv<<<2048, 64, 0, stream>>>(Whh0, Whh0p);
    pack_conv<<<2048, 64, 0, stream>>>(Wih1, Wih1p);
    pack_conv<<<2048, 64, 0, stream>>>(Whh1, Whh1p);
    pack_bias<<<8, 256, 0, stream>>>(bih0, bhh0, bih1, bhh1, b0p, b1p);
    gather_x<<<2048, 256, 0, stream>>>(seq, emb, Xbf);
    init_c0<<<64, 256, 0, stream>>>(word, emb, w2hW, w2hb, c0s, c1s, h0A, h1A);

    // G0 = X @ Wih0p^T + b0p (packed gate order)   [4096 x 2048], K=512
    gemm_bt128<<<32 * 16, 256, 0, stream>>>(Xbf, Wih0p, G0, b0p, nullptr,
                                            512, GDIM, (long)GDIM, 16);

    // skewed recurrence: layer0 step t || layer1 step t-1
    for (int t = 0; t <= T_STEPS; ++t)
        lstm_step_mfma<<<32, 256, 0, stream>>>(G0, Whh0p, Wih1p, Whh1p, b1p,
                                               y0bf, y1bf, h0A, h0B, c0s,
                                               h1A, h1B, c1s, hf, t);

    // decoded = y1 @ dec_W^T + dec_b   [4096 x 50000], K=512
    gemm_bt128<<<32 * 391, 256, 0, stream>>>(y1bf, decWb, out, dec_b, nullptr,
                                             512, VOCAB, (long)VOCAB, 391);

    finalize_states<<<256, 256, 0, stream>>>(hf, c0s, c1s, out);
}

// Round 3
// 1462.944 us; speedup vs baseline: 10.3568x; 2.0278x over previous
//
#include <hip/hip_runtime.h>
#include <hip/hip_bf16.h>
#include <cstdint>

// Problem dims
#define T_STEPS 128
#define BATCH   32
#define VOCAB   50000
#define EDIM    512
#define HDIM    512
#define GDIM    2048          // 4*H
#define MROWS   4096          // T*B
#define VPAD    50048         // 391 * 128 (padded N for decode GEMM)

typedef short bf16x8 __attribute__((ext_vector_type(8)));
typedef float f32x4  __attribute__((ext_vector_type(4)));
typedef unsigned short us4 __attribute__((ext_vector_type(4)));
typedef unsigned short us8 __attribute__((ext_vector_type(8)));

__device__ __forceinline__ float sigmoidf_(float x) { return 1.0f / (1.0f + expf(-x)); }

// round-to-nearest-even fp32 -> bf16 bits
__device__ __forceinline__ unsigned short f2bf(float f) {
    unsigned int u = __float_as_uint(f);
    u = (u + 0x7fffu + ((u >> 16) & 1u)) >> 16;
    return (unsigned short)u;
}

// ---------------------------------------------------------------------------
// Prologue kernels
// ---------------------------------------------------------------------------

// dec_W [50000x512] fp32 -> [50048x512] bf16 with zero pad rows
__global__ __launch_bounds__(256) void conv_decw(const float* __restrict__ src,
                                                 unsigned short* __restrict__ dst) {
    long i = ((long)blockIdx.x * 256 + threadIdx.x) * 8;
    if (i >= (long)VPAD * EDIM) return;
    long row = i >> 9;
    us8 v;
    if (row < VOCAB) {
        float4 a = *(const float4*)(src + i);
        float4 b = *(const float4*)(src + i + 4);
        v[0] = f2bf(a.x); v[1] = f2bf(a.y); v[2] = f2bf(a.z); v[3] = f2bf(a.w);
        v[4] = f2bf(b.x); v[5] = f2bf(b.y); v[6] = f2bf(b.z); v[7] = f2bf(b.w);
    } else {
        v = (us8)0;
    }
    *(us8*)(dst + i) = v;
}

// Gate-interleaved pack+convert: dst[n'][k] = bf16(src[(n'&3)*512 + (n'>>2)][k])
__global__ __launch_bounds__(64) void pack_conv(const float* __restrict__ src,
                                                unsigned short* __restrict__ dst) {
    const int n = blockIdx.x;                       // packed row 0..2047
    const int orig = (n & 3) * 512 + (n >> 2);
    const int k = threadIdx.x * 8;
    const float* s = src + (long)orig * 512 + k;
    float4 a = *(const float4*)s;
    float4 b = *(const float4*)(s + 4);
    us8 v;
    v[0] = f2bf(a.x); v[1] = f2bf(a.y); v[2] = f2bf(a.z); v[3] = f2bf(a.w);
    v[4] = f2bf(b.x); v[5] = f2bf(b.y); v[6] = f2bf(b.z); v[7] = f2bf(b.w);
    *(us8*)(dst + (long)n * 512 + k) = v;
}

// packed bias sums
__global__ __launch_bounds__(256) void pack_bias(const float* __restrict__ bih0,
                                                 const float* __restrict__ bhh0,
                                                 const float* __restrict__ bih1,
                                                 const float* __restrict__ bhh1,
                                                 float* __restrict__ b0p,
                                                 float* __restrict__ b1p) {
    const int n = blockIdx.x * 256 + threadIdx.x;   // 0..2047
    const int orig = (n & 3) * 512 + (n >> 2);
    b0p[n] = bih0[orig] + bhh0[orig];
    b1p[n] = bih1[orig] + bhh1[orig];
}

// X[r, :] = bf16(emb[seq[r], :]) for r in [0, T*B)
__global__ __launch_bounds__(256) void gather_x(const int* __restrict__ seq,
                                                const float* __restrict__ emb,
                                                unsigned short* __restrict__ Xbf) {
    long i = ((long)blockIdx.x * 256 + threadIdx.x) * 4;
    if (i >= (long)MROWS * EDIM) return;
    int r   = (int)(i >> 9);
    int col = (int)(i & 511);
    const float* er = emb + (long)seq[r] * EDIM + col;
    float4 e = *(const float4*)er;
    us4 v;
    v[0] = f2bf(e.x); v[1] = f2bf(e.y); v[2] = f2bf(e.z); v[3] = f2bf(e.w);
    *(us4*)(Xbf + i) = v;
}

// c0[b,h] = emb[word[b]] . w2h_W[h] + w2h_b[h]; both layers start with c0, h=0 (bf16)
__global__ __launch_bounds__(256) void init_c0(const int* __restrict__ word,
                                               const float* __restrict__ emb,
                                               const float* __restrict__ w2hW,
                                               const float* __restrict__ w2hb,
                                               float* __restrict__ c0s, float* __restrict__ c1s,
                                               unsigned short* __restrict__ h0A,
                                               unsigned short* __restrict__ h1A) {
    const int idx = blockIdx.x * 256 + threadIdx.x;   // 0..16383
    const int b = idx >> 9, hh = idx & 511;
    const float* er = emb + (long)word[b] * EDIM;
    const float* wr = w2hW + (long)hh * EDIM;
    float acc = w2hb[hh];
    #pragma unroll 4
    for (int k = 0; k < EDIM; k += 4) {
        float4 e4 = *(const float4*)(er + k);
        float4 w4 = *(const float4*)(wr + k);
        acc += e4.x * w4.x + e4.y * w4.y + e4.z * w4.z + e4.w * w4.w;
    }
    c0s[idx] = acc;
    c1s[idx] = acc;
    h0A[idx] = 0;
    h1A[idx] = 0;
}

// ---------------------------------------------------------------------------
// MFMA GEMM: C[m,n] = sum_k A[m,k]*Bt[n,k] (+bias1[n] +bias2[n])
// ntstore=1 -> nontemporal C stores (streaming output, don't pollute L2/L3)
// ---------------------------------------------------------------------------
__global__ __launch_bounds__(256) void gemm_bt128(const unsigned short* __restrict__ A,
                                                  const unsigned short* __restrict__ Bt,
                                                  float* __restrict__ C,
                                                  const float* __restrict__ bias1,
                                                  const float* __restrict__ bias2,
                                                  int K, int Nreal, long ldc, int ntn,
                                                  int ntstore) {
    __shared__ __align__(16) unsigned short As[128 * 64];
    __shared__ __align__(16) unsigned short Bs[128 * 64];
    const int tid  = threadIdx.x;
    const long m0  = (long)(blockIdx.x / ntn) * 128;
    const long n0  = (long)(blockIdx.x % ntn) * 128;
    const int lane = tid & 63;
    const int wave = tid >> 6;
    const int wr = wave >> 1, wc = wave & 1;
    const int fr = lane & 15, fq = lane >> 4;

    f32x4 acc[4][4];
    #pragma unroll
    for (int i = 0; i < 4; ++i)
        #pragma unroll
        for (int j = 0; j < 4; ++j) acc[i][j] = (f32x4)0.0f;

    const int srow = tid >> 3;
    const int scol = (tid & 7) * 8;

    for (int kt = 0; kt < K; kt += 64) {
        #pragma unroll
        for (int i = 0; i < 4; ++i) {
            const unsigned short* ga = A  + (m0 + i * 32 + srow) * K + kt + scol;
            const unsigned short* gb = Bt + (n0 + i * 32 + srow) * K + kt + scol;
            __builtin_amdgcn_global_load_lds((const __attribute__((address_space(1))) void*)ga,
                                             (__attribute__((address_space(3))) void*)(As + i * 2048 + tid * 8),
                                             16, 0, 0);
            __builtin_amdgcn_global_load_lds((const __attribute__((address_space(1))) void*)gb,
                                             (__attribute__((address_space(3))) void*)(Bs + i * 2048 + tid * 8),
                                             16, 0, 0);
        }
        asm volatile("s_waitcnt vmcnt(0)" ::: "memory");
        __syncthreads();
        #pragma unroll
        for (int ks = 0; ks < 64; ks += 32) {
            bf16x8 af[4], bfr[4];
            #pragma unroll
            for (int mi = 0; mi < 4; ++mi)
                af[mi] = *(const bf16x8*)&As[(wr * 64 + mi * 16 + fr) * 64 + ks + fq * 8];
            #pragma unroll
            for (int ni = 0; ni < 4; ++ni)
                bfr[ni] = *(const bf16x8*)&Bs[(wc * 64 + ni * 16 + fr) * 64 + ks + fq * 8];
            #pragma unroll
            for (int mi = 0; mi < 4; ++mi)
                #pragma unroll
                for (int ni = 0; ni < 4; ++ni)
                    acc[mi][ni] = __builtin_amdgcn_mfma_f32_16x16x32_bf16(af[mi], bfr[ni], acc[mi][ni], 0, 0, 0);
        }
        __syncthreads();
    }

    #pragma unroll
    for (int mi = 0; mi < 4; ++mi) {
        const long row = m0 + wr * 64 + mi * 16 + fq * 4;
        #pragma unroll
        for (int ni = 0; ni < 4; ++ni) {
            const long col = n0 + wc * 64 + ni * 16 + fr;
            if (col < Nreal) {
                float bs = (bias1 ? bias1[col] : 0.0f) + (bias2 ? bias2[col] : 0.0f);
                #pragma unroll
                for (int r = 0; r < 4; ++r) {
                    float v = acc[mi][ni][r] + bs;
                    float* p = &C[(row + r) * ldc + col];
                    if (ntstore) __builtin_nontemporal_store(v, p);
                    else *p = v;
                }
            }
        }
    }
}

// ---------------------------------------------------------------------------
// LSTM step, wave-level K-split (skewed): blocks 0..63 layer0 step t (32 packed
// cols each, 8 waves x K=64), blocks 64..127 layer1 step t-1 (32 cols, waves
// 0-3: y0@Wih1^T K=128 chunks, waves 4-7: h@Whh1^T K=128 chunks). All fragment
// loads fully unrolled -> one latency exposure. Partials reduced via LDS.
// ---------------------------------------------------------------------------
__global__ __launch_bounds__(512) void lstm_step2(
        const float* __restrict__ G0,              // [4096][2048] packed (b0p folded)
        const unsigned short* __restrict__ Whh0p,  // [2048][512] packed bf16
        const unsigned short* __restrict__ Wih1p,
        const unsigned short* __restrict__ Whh1p,
        const float* __restrict__ b1p,             // [2048] packed bias sum layer1
        unsigned short* __restrict__ y0bf,         // [T][32][512] bf16
        unsigned short* __restrict__ y1bf,
        unsigned short* __restrict__ h0A, unsigned short* __restrict__ h0B,
        float* __restrict__ c0s,
        unsigned short* __restrict__ h1A, unsigned short* __restrict__ h1B,
        float* __restrict__ c1s,
        float* __restrict__ hf,                    // [2][32][512] fp32 final h
        int t) {
    __shared__ float part[8][32][32];              // 32 KB partial tiles
    int bid = blockIdx.x;
    const int tid  = threadIdx.x;
    const int wv   = tid >> 6, lane = tid & 63;
    const int fr   = lane & 15, fq = lane >> 4;

    int layer, tt, cg;
    if (bid < 64) { layer = 0; tt = t;     if (tt >= T_STEPS) return; cg = bid; }
    else          { layer = 1; tt = t - 1; if (tt < 0) return;       cg = bid - 64; }

    const unsigned short* hin;
    unsigned short* hout;
    float* cs;
    if (layer == 0) { hin = (tt & 1) ? h0B : h0A; hout = (tt & 1) ? h0A : h0B; cs = c0s; }
    else            { hin = (tt & 1) ? h1B : h1A; hout = (tt & 1) ? h1A : h1B; cs = c1s; }

    const int n_base = cg * 32;

    f32x4 acc[2][2];
    acc[0][0] = (f32x4)0.0f; acc[0][1] = (f32x4)0.0f;
    acc[1][0] = (f32x4)0.0f; acc[1][1] = (f32x4)0.0f;

    if (layer == 0) {
        // waves 0..7, K chunk = 64 each, 2 fully-unrolled kt iters
        const int kbase = wv * 64;
        const unsigned short* A0 = hin + fr * 512 + kbase + fq * 8;
        const unsigned short* A1 = A0 + 16 * 512;
        const unsigned short* B0 = Whh0p + (long)(n_base + fr) * 512 + kbase + fq * 8;
        const unsigned short* B1 = B0 + 16 * 512;
        #pragma unroll
        for (int i = 0; i < 2; ++i) {
            bf16x8 a0 = *(const bf16x8*)(A0 + i * 32);
            bf16x8 a1 = *(const bf16x8*)(A1 + i * 32);
            bf16x8 b0 = *(const bf16x8*)(B0 + i * 32);
            bf16x8 b1 = *(const bf16x8*)(B1 + i * 32);
            acc[0][0] = __builtin_amdgcn_mfma_f32_16x16x32_bf16(a0, b0, acc[0][0], 0, 0, 0);
            acc[0][1] = __builtin_amdgcn_mfma_f32_16x16x32_bf16(a0, b1, acc[0][1], 0, 0, 0);
            acc[1][0] = __builtin_amdgcn_mfma_f32_16x16x32_bf16(a1, b0, acc[1][0], 0, 0, 0);
            acc[1][1] = __builtin_amdgcn_mfma_f32_16x16x32_bf16(a1, b1, acc[1][1], 0, 0, 0);
        }
    } else {
        // waves 0..3: y0[tt] @ Wih1^T ; waves 4..7: h1 @ Whh1^T ; K chunk = 128
        const unsigned short* Aop = (wv < 4) ? (y0bf + (long)tt * (BATCH * HDIM)) : hin;
        const unsigned short* Bop = (wv < 4) ? Wih1p : Whh1p;
        const int kbase = (wv & 3) * 128;
        const unsigned short* A0 = Aop + fr * 512 + kbase + fq * 8;
        const unsigned short* A1 = A0 + 16 * 512;
        const unsigned short* B0 = Bop + (long)(n_base + fr) * 512 + kbase + fq * 8;
        const unsigned short* B1 = B0 + 16 * 512;
        #pragma unroll
        for (int i = 0; i < 4; ++i) {
            bf16x8 a0 = *(const bf16x8*)(A0 + i * 32);
            bf16x8 a1 = *(const bf16x8*)(A1 + i * 32);
            bf16x8 b0 = *(const bf16x8*)(B0 + i * 32);
            bf16x8 b1 = *(const bf16x8*)(B1 + i * 32);
            acc[0][0] = __builtin_amdgcn_mfma_f32_16x16x32_bf16(a0, b0, acc[0][0], 0, 0, 0);
            acc[0][1] = __builtin_amdgcn_mfma_f32_16x16x32_bf16(a0, b1, acc[0][1], 0, 0, 0);
            acc[1][0] = __builtin_amdgcn_mfma_f32_16x16x32_bf16(a1, b0, acc[1][0], 0, 0, 0);
            acc[1][1] = __builtin_amdgcn_mfma_f32_16x16x32_bf16(a1, b1, acc[1][1], 0, 0, 0);
        }
    }

    // partial tiles -> LDS
    #pragma unroll
    for (int mi = 0; mi < 2; ++mi)
        #pragma unroll
        for (int ni = 0; ni < 2; ++ni)
            #pragma unroll
            for (int r = 0; r < 4; ++r)
                part[wv][mi * 16 + fq * 4 + r][ni * 16 + fr] = acc[mi][ni][r];
    __syncthreads();

    // reduce + pointwise: threads 0..255, one (batch, unit) each
    if (tid < 256) {
        const int b = tid >> 3, u = tid & 7;
        float4 g4 = *(const float4*)&part[0][b][u * 4];
        #pragma unroll
        for (int w = 1; w < 8; ++w) {
            float4 p4 = *(const float4*)&part[w][b][u * 4];
            g4.x += p4.x; g4.y += p4.y; g4.z += p4.z; g4.w += p4.w;
        }
        float4 ad;
        if (layer == 0) ad = *(const float4*)(G0 + ((long)tt * BATCH + b) * GDIM + n_base + u * 4);
        else            ad = *(const float4*)(b1p + n_base + u * 4);
        const float vi = g4.x + ad.x, vf = g4.y + ad.y;
        const float vg = g4.z + ad.z, vo = g4.w + ad.w;
        const int si = b * HDIM + (n_base >> 2) + u;
        float c = sigmoidf_(vf) * cs[si] + sigmoidf_(vi) * tanhf(vg);
        float h = sigmoidf_(vo) * tanhf(c);
        cs[si] = c;
        const unsigned short hb = f2bf(h);
        hout[si] = hb;
        if (layer == 0) y0bf[(long)tt * (BATCH * HDIM) + si] = hb;
        else            y1bf[(long)tt * (BATCH * HDIM) + si] = hb;
        if (tt == T_STEPS - 1) hf[layer * (BATCH * HDIM) + si] = h;
    }
}

// d_out tail: [h_f0 | h_f1 | c_f0 | c_f1], 16384 floats each
__global__ __launch_bounds__(256) void finalize_states(const float* __restrict__ hf,
                                                       const float* __restrict__ c0s,
                                                       const float* __restrict__ c1s,
                                                       float* __restrict__ out) {
    const int idx = blockIdx.x * 256 + threadIdx.x;   // 0..65535
    const long base = (long)MROWS * VOCAB;
    float v;
    if (idx < 32768)      v = hf[idx];
    else if (idx < 49152) v = c0s[idx - 32768];
    else                  v = c1s[idx - 49152];
    out[base + idx] = v;
}

// ---------------------------------------------------------------------------
extern "C" void kernel_launch(void* const* d_in, const int* in_sizes, int n_in,
                              void* d_out, int out_size, void* d_ws, size_t ws_size,
                              hipStream_t stream) {
    const int*   word  = (const int*)d_in[0];
    const int*   seq   = (const int*)d_in[1];
    const float* emb   = (const float*)d_in[2];
    const float* w2hW  = (const float*)d_in[3];
    const float* w2hb  = (const float*)d_in[4];
    const float* Wih0  = (const float*)d_in[5];
    const float* Whh0  = (const float*)d_in[6];
    const float* bih0  = (const float*)d_in[7];
    const float* bhh0  = (const float*)d_in[8];
    const float* Wih1  = (const float*)d_in[9];
    const float* Whh1  = (const float*)d_in[10];
    const float* bih1  = (const float*)d_in[11];
    const float* bhh1  = (const float*)d_in[12];
    const float* dec_W = (const float*)d_in[13];
    const float* dec_b = (const float*)d_in[14];
    float* out = (float*)d_out;

    char* ws = (char*)d_ws;
    size_t off = 0;
    float*          G0    = (float*)(ws + off);          off += (size_t)MROWS * GDIM * 4;   // 33.5 MB
    unsigned short* Xbf   = (unsigned short*)(ws + off); off += (size_t)MROWS * EDIM * 2;   //  4.2 MB
    unsigned short* Wih0p = (unsigned short*)(ws + off); off += (size_t)GDIM  * EDIM * 2;   //  2.1 MB
    unsigned short* Whh0p = (unsigned short*)(ws + off); off += (size_t)GDIM  * HDIM * 2;   //  2.1 MB
    unsigned short* Wih1p = (unsigned short*)(ws + off); off += (size_t)GDIM  * HDIM * 2;   //  2.1 MB
    unsigned short* Whh1p = (unsigned short*)(ws + off); off += (size_t)GDIM  * HDIM * 2;   //  2.1 MB
    unsigned short* decWb = (unsigned short*)(ws + off); off += (size_t)VPAD  * EDIM * 2;   // 51.2 MB
    unsigned short* y0bf  = (unsigned short*)(ws + off); off += (size_t)MROWS * HDIM * 2;   //  4.2 MB
    unsigned short* y1bf  = (unsigned short*)(ws + off); off += (size_t)MROWS * HDIM * 2;   //  4.2 MB
    float* b0p = (float*)(ws + off); off += (size_t)GDIM * 4;
    float* b1p = (float*)(ws + off); off += (size_t)GDIM * 4;
    unsigned short* h0A = (unsigned short*)(ws + off); off += (size_t)BATCH * HDIM * 2;
    unsigned short* h0B = (unsigned short*)(ws + off); off += (size_t)BATCH * HDIM * 2;
    unsigned short* h1A = (unsigned short*)(ws + off); off += (size_t)BATCH * HDIM * 2;
    unsigned short* h1B = (unsigned short*)(ws + off); off += (size_t)BATCH * HDIM * 2;
    float* c0s = (float*)(ws + off); off += (size_t)BATCH * HDIM * 4;
    float* c1s = (float*)(ws + off); off += (size_t)BATCH * HDIM * 4;
    float* hf  = (float*)(ws + off); off += (size_t)2 * BATCH * HDIM * 4;
    // total ~106 MB of d_ws

    // prologue (parallel)
    conv_decw<<<12512, 256, 0, stream>>>(dec_W, decWb);
    pack_conv<<<2048, 64, 0, stream>>>(Wih0, Wih0p);
    pack_conv<<<2048, 64, 0, stream>>>(Whh0, Whh0p);
    pack_conv<<<2048, 64, 0, stream>>>(Wih1, Wih1p);
    pack_conv<<<2048, 64, 0, stream>>>(Whh1, Whh1p);
    pack_bias<<<8, 256, 0, stream>>>(bih0, bhh0, bih1, bhh1, b0p, b1p);
    gather_x<<<2048, 256, 0, stream>>>(seq, emb, Xbf);
    init_c0<<<64, 256, 0, stream>>>(word, emb, w2hW, w2hb, c0s, c1s, h0A, h1A);

    // G0 = X @ Wih0p^T + b0p (packed gate order)   [4096 x 2048], K=512
    gemm_bt128<<<32 * 16, 256, 0, stream>>>(Xbf, Wih0p, G0, b0p, nullptr,
                                            512, GDIM, (long)GDIM, 16, 0);

    // skewed recurrence: layer0 step t || layer1 step t-1
    for (int t = 0; t <= T_STEPS; ++t)
        lstm_step2<<<128, 512, 0, stream>>>(G0, Whh0p, Wih1p, Whh1p, b1p,
                                            y0bf, y1bf, h0A, h0B, c0s,
                                            h1A, h1B, c1s, hf, t);

    // decoded = y1 @ dec_W^T + dec_b   [4096 x 50000], K=512  (nontemporal C)
    gemm_bt128<<<32 * 391, 256, 0, stream>>>(y1bf, decWb, out, dec_b, nullptr,
                                             512, VOCAB, (long)VOCAB, 391, 1);

    finalize_states<<<256, 256, 0, stream>>>(hf, c0s, c1s, out);
}